// Round 14
// baseline (141.548 us; speedup 1.0000x reference)
//
#include <hip/hip_runtime.h>
#include <hip/hip_bf16.h>
#include <math.h>

#define Cdim 256
#define Hn 8
#define Bn 2
#define Sn 4096
#define Dh 32
#define GN_EPS 1e-5f
#define QK_SCALE 0.42044820762685725f   // 32^(-1/4), applied to BOTH q and k like the reference
#define LOG2E 1.4426950408889634f
#define NSPLIT 4
#define BHSZ (Sn * Dh)                  // elems per (b,h) in swizzled K/V
#define HLP 264                         // hl pitch in shorts (16B-aligned rows)

typedef __attribute__((ext_vector_type(8))) short short8;
typedef __attribute__((ext_vector_type(4))) float floatx4;
typedef __attribute__((ext_vector_type(16))) float floatx16;

__device__ __forceinline__ unsigned short f2bu(float x) {
  union { float f; unsigned u; } v; v.f = x;
  unsigned r = v.u + 0x7fffu + ((v.u >> 16) & 1u);  // RNE
  return (unsigned short)(r >> 16);
}

// pack 16 f32 probs -> two bf16x8 B-fragments via cvt_pk + permlane32_swap (T12)
__device__ __forceinline__ void pack_pt(const floatx16& p, short8& f0, short8& f1) {
  unsigned c0, c1, c2, c3, c4, c5, c6, c7;
  asm("v_cvt_pk_bf16_f32 %0, %1, %2" : "=v"(c0) : "v"(p[0]),  "v"(p[1]));
  asm("v_cvt_pk_bf16_f32 %0, %1, %2" : "=v"(c1) : "v"(p[2]),  "v"(p[3]));
  asm("v_cvt_pk_bf16_f32 %0, %1, %2" : "=v"(c2) : "v"(p[4]),  "v"(p[5]));
  asm("v_cvt_pk_bf16_f32 %0, %1, %2" : "=v"(c3) : "v"(p[6]),  "v"(p[7]));
  asm("v_cvt_pk_bf16_f32 %0, %1, %2" : "=v"(c4) : "v"(p[8]),  "v"(p[9]));
  asm("v_cvt_pk_bf16_f32 %0, %1, %2" : "=v"(c5) : "v"(p[10]), "v"(p[11]));
  asm("v_cvt_pk_bf16_f32 %0, %1, %2" : "=v"(c6) : "v"(p[12]), "v"(p[13]));
  asm("v_cvt_pk_bf16_f32 %0, %1, %2" : "=v"(c7) : "v"(p[14]), "v"(p[15]));
  asm("v_permlane32_swap_b32 %0, %1" : "+v"(c0), "+v"(c2));
  asm("v_permlane32_swap_b32 %0, %1" : "+v"(c1), "+v"(c3));
  asm("v_permlane32_swap_b32 %0, %1" : "+v"(c4), "+v"(c6));
  asm("v_permlane32_swap_b32 %0, %1" : "+v"(c5), "+v"(c7));
  union { unsigned u[4]; short8 s8; } a, b;
  a.u[0] = c0; a.u[1] = c1; a.u[2] = c2; a.u[3] = c3;
  b.u[0] = c4; b.u[1] = c5; b.u[2] = c6; b.u[3] = c7;
  f0 = a.s8; f1 = b.s8;
}

// ---------------- fused: GroupNorm partial stats (blocks 0-511) + weight cast (512-767) ----
__global__ void k_pre(const float* __restrict__ x,
                      const float* __restrict__ wq, const float* __restrict__ wk,
                      const float* __restrict__ wv, const float* __restrict__ wo,
                      float* __restrict__ part, unsigned short* __restrict__ wall) {
  if (blockIdx.x < 512) {
    int b = blockIdx.x >> 8;
    int base = (blockIdx.x & 255) * 4096 + b * (Cdim * Sn);
    float s = 0.f, ss = 0.f;
#pragma unroll
    for (int k = 0; k < 16; ++k) {
      float v = x[base + k * 256 + threadIdx.x];
      s += v; ss += v * v;
    }
    for (int off = 32; off; off >>= 1) { s += __shfl_down(s, off); ss += __shfl_down(ss, off); }
    __shared__ float as[4], bs[4];
    int w = threadIdx.x >> 6;
    if ((threadIdx.x & 63) == 0) { as[w] = s; bs[w] = ss; }
    __syncthreads();
    if (threadIdx.x == 0) {
      part[blockIdx.x * 2]     = as[0] + as[1] + as[2] + as[3];
      part[blockIdx.x * 2 + 1] = bs[0] + bs[1] + bs[2] + bs[3];
    }
  } else {
    int i = (blockIdx.x - 512) * 256 + threadIdx.x;  // 65536 total
    wall[0 * 65536 + i] = f2bu(wq[i]);
    wall[1 * 65536 + i] = f2bu(wk[i]);
    wall[2 * 65536 + i] = f2bu(wv[i]);
    wall[3 * 65536 + i] = f2bu(wo[i]);
  }
}

// ---------------- fused GroupNorm + QKV projection (R12, unchanged) ----------------
__global__ void k_nqkv(const float* __restrict__ x, const float* __restrict__ gw,
                       const float* __restrict__ gb, const float* __restrict__ part,
                       const unsigned short* __restrict__ wall,
                       const float* __restrict__ bq, const float* __restrict__ bk,
                       const float* __restrict__ bv,
                       unsigned short* __restrict__ qf, unsigned short* __restrict__ kswz,
                       unsigned short* __restrict__ vswz) {
  int sb = blockIdx.x;                  // 0..127, rows mBase..mBase+63
  int mBase = sb * 64;
  int b = sb >> 6;
  int proj = blockIdx.y >> 1, half = blockIdx.y & 1;
  int w = threadIdx.x >> 6, lane = threadIdx.x & 63;
  int lr = lane & 15, lg = lane >> 4;

  __shared__ float as[4], bs[4];
  {
    float s  = part[(b * 256 + threadIdx.x) * 2];
    float ss = part[(b * 256 + threadIdx.x) * 2 + 1];
    for (int off = 32; off; off >>= 1) { s += __shfl_down(s, off); ss += __shfl_down(ss, off); }
    if ((threadIdx.x & 63) == 0) { as[w] = s; bs[w] = ss; }
  }
  __syncthreads();
  const float invN = 1.f / (float)(Cdim * Sn);
  float mean = (as[0] + as[1] + as[2] + as[3]) * invN;
  float var  = (bs[0] + bs[1] + bs[2] + bs[3]) * invN - mean * mean;
  float rstd = rsqrtf(var + GN_EPS);

  __shared__ unsigned short hl[64][HLP];
  {
    int s0 = mBase & 4095;
    int rg = threadIdx.x >> 6;
#pragma unroll
    for (int i = 0; i < 32; ++i) {
      int cl = i * 8 + rg * 2;
      float v0 = x[((size_t)(b * Cdim + cl))     * Sn + s0 + lane];
      float v1 = x[((size_t)(b * Cdim + cl + 1)) * Sn + s0 + lane];
      float y0 = (v0 - mean) * rstd * gw[cl]     + gb[cl];
      float y1 = (v1 - mean) * rstd * gw[cl + 1] + gb[cl + 1];
      unsigned pkv = (unsigned)f2bu(y0) | ((unsigned)f2bu(y1) << 16);
      *(unsigned*)&hl[lane][cl] = pkv;
    }
  }
  __syncthreads();

  const unsigned short* W = wall + proj * 65536;
  __shared__ float tl[64][65];
  for (int sub = 0; sub < 2; ++sub) {
    int n0 = half * 128 + sub * 64;
    floatx4 acc[4] = {};
    for (int k0 = 0; k0 < 256; k0 += 32) {
      short8 a = *(const short8*)&hl[w * 16 + lr][k0 + lg * 8];
#pragma unroll
      for (int nt = 0; nt < 4; ++nt) {
        short8 bfr = *(const short8*)(W + (size_t)(n0 + nt * 16 + lr) * 256 + k0 + lg * 8);
        acc[nt] = __builtin_amdgcn_mfma_f32_16x16x32_bf16(a, bfr, acc[nt], 0, 0, 0);
      }
    }
    if (sub) __syncthreads();
    {
      const float* bias = (proj == 0) ? bq : (proj == 1 ? bk : bv);
      float scale = (proj == 0) ? (QK_SCALE * LOG2E) : (proj == 1 ? QK_SCALE : 1.f);
#pragma unroll
      for (int nt = 0; nt < 4; ++nt) {
        int nl = nt * 16 + lr;
        float bias_n = bias[n0 + nl];
#pragma unroll
        for (int j = 0; j < 4; ++j)
          tl[nl][w * 16 + lg * 4 + j] = (acc[nt][j] + bias_n) * scale;
      }
    }
    __syncthreads();
    if (proj < 2) {
#pragma unroll
      for (int i = 0; i < 2; ++i) {
        int t = threadIdx.x + 256 * i;
        int s_l = t & 63, oct = t >> 6;
        int m = mBase + s_l, bb = m >> 12, s = m & 4095;
        int cp = n0 + oct * 8;
        int hh = cp >> 5, dd0 = cp & 31;
        int bh = bb * Hn + hh;
        union { unsigned short us[8]; short8 s8; } pk;
#pragma unroll
        for (int e = 0; e < 8; ++e) pk.us[e] = f2bu(tl[oct * 8 + e][s_l]);
        if (proj == 0) {
          *(short8*)(qf + ((size_t)bh * Sn + s) * Dh + dd0) = pk.s8;
        } else {
          int fr = dd0 >> 4, ddl = (dd0 >> 3) & 1;
          size_t off = (size_t)bh * BHSZ +
                       (size_t)(((((s >> 5) * 2 + fr) * 64) + (s & 31) + 32 * ddl) * 8);
          *(short8*)(kswz + off) = pk.s8;
        }
      }
    } else {
#pragma unroll
      for (int i = 0; i < 2; ++i) {
        int t = threadIdx.x + 256 * i;
        int dd_l = t & 63, soct = t >> 6;
        int cp = n0 + dd_l;
        int hh = cp >> 5, dd = cp & 31;
        int m = mBase + soct * 8, bb = m >> 12, s = m & 4095;
        int bh = bb * Hn + hh;
        union { unsigned short us[8]; short8 s8; } pk;
#pragma unroll
        for (int e = 0; e < 8; ++e) pk.us[e] = f2bu(tl[dd_l][soct * 8 + e]);
        size_t off = (size_t)bh * BHSZ +
                     (size_t)(((((s >> 5) * 2 + ((s >> 4) & 1)) * 64) + dd + 32 * ((s >> 3) & 1)) * 8);
        *(short8*)(vswz + off) = pk.s8;
      }
    }
  }
}

// ---------------- flash attention: 64q/wave, split-K x4, depth-2 prefetch, no setprio ----
// R10 body minus s_setprio (uniform waves -> setprio convoy effect, cf T5/m190) plus
// 2-step-deep register prefetch (K reloaded right after QK MFMAs consume it, V after PV;
// ~1.5 steps of slack vs <1 before) to cover loaded-L2 latency.
__global__ __launch_bounds__(256, 4) void k_flash(
    const unsigned short* __restrict__ qf, const unsigned short* __restrict__ kswz,
    const unsigned short* __restrict__ vswz, unsigned short* __restrict__ of) {
  int w = threadIdx.x >> 6, lane = threadIdx.x & 63;
  int l31 = lane & 31, hi = lane >> 5;
  int lin = blockIdx.x;                                // 0..1023
  int xcd = lin & 7, slot = lin >> 3;                  // 128 slots per XCD
  int bh = xcd + 8 * (slot >> 6);                      // 2 bh per XCD
  int q0 = (slot & 63) * 64;
  const unsigned short* Q = qf + (size_t)bh * Sn * Dh;

  short8 qa0 = *(const short8*)(Q + (size_t)(q0 + l31) * Dh + hi * 8);
  short8 qa1 = *(const short8*)(Q + (size_t)(q0 + l31) * Dh + 16 + hi * 8);
  short8 qc0 = *(const short8*)(Q + (size_t)(q0 + 32 + l31) * Dh + hi * 8);
  short8 qc1 = *(const short8*)(Q + (size_t)(q0 + 32 + l31) * Dh + 16 + hi * 8);

  floatx16 oaccA = {}, oaccB = {};  // O^T[d][q]: col q = l31, row d = (r&3)+8*(r>>2)+4*hi
  float lA = 0.f, lB = 0.f;
  const floatx16 zero16 = {};
  const unsigned short* Kc = kswz + (size_t)bh * BHSZ + (size_t)(w * 32) * 1024;
  const unsigned short* Vc = vswz + (size_t)bh * BHSZ + (size_t)(w * 32) * 1024;
  const int lofs = lane * 8;

  // depth-2 prefetch: two live K/V buffers
  short8 kA0 = *(const short8*)(Kc + lofs);
  short8 kA1 = *(const short8*)(Kc + 512 + lofs);
  short8 vA0 = *(const short8*)(Vc + lofs);
  short8 vA1 = *(const short8*)(Vc + 512 + lofs);
  short8 kB0 = *(const short8*)(Kc + 1024 + lofs);
  short8 kB1 = *(const short8*)(Kc + 1024 + 512 + lofs);
  short8 vB0 = *(const short8*)(Vc + 1024 + lofs);
  short8 vB1 = *(const short8*)(Vc + 1024 + 512 + lofs);

#define FSTEP(K0, K1, V0, V1, NX)                                                   \
  {                                                                                 \
    floatx16 sA = __builtin_amdgcn_mfma_f32_32x32x16_bf16(K0, qa0, zero16, 0, 0, 0);\
    sA = __builtin_amdgcn_mfma_f32_32x32x16_bf16(K1, qa1, sA, 0, 0, 0);             \
    floatx16 sB = __builtin_amdgcn_mfma_f32_32x32x16_bf16(K0, qc0, zero16, 0, 0, 0);\
    sB = __builtin_amdgcn_mfma_f32_32x32x16_bf16(K1, qc1, sB, 0, 0, 0);             \
    K0 = *(const short8*)(Kc + (NX) * 1024 + lofs);                                 \
    K1 = *(const short8*)(Kc + (NX) * 1024 + 512 + lofs);                           \
    _Pragma("unroll")                                                               \
    for (int i = 0; i < 16; ++i) sA[i] = __builtin_amdgcn_exp2f(sA[i]);             \
    _Pragma("unroll")                                                               \
    for (int i = 0; i < 16; ++i) sB[i] = __builtin_amdgcn_exp2f(sB[i]);             \
    {                                                                               \
      float t0 = (sA[0] + sA[1]) + (sA[2] + sA[3]);                                 \
      float t1 = (sA[4] + sA[5]) + (sA[6] + sA[7]);                                 \
      float t2 = (sA[8] + sA[9]) + (sA[10] + sA[11]);                               \
      float t3 = (sA[12] + sA[13]) + (sA[14] + sA[15]);                             \
      lA += (t0 + t1) + (t2 + t3);                                                  \
      float u0 = (sB[0] + sB[1]) + (sB[2] + sB[3]);                                 \
      float u1 = (sB[4] + sB[5]) + (sB[6] + sB[7]);                                 \
      float u2 = (sB[8] + sB[9]) + (sB[10] + sB[11]);                               \
      float u3 = (sB[12] + sB[13]) + (sB[14] + sB[15]);                             \
      lB += (u0 + u1) + (u2 + u3);                                                  \
    }                                                                               \
    short8 fA0, fA1, fB0, fB1;                                                      \
    pack_pt(sA, fA0, fA1);                                                          \
    pack_pt(sB, fB0, fB1);                                                          \
    oaccA = __builtin_amdgcn_mfma_f32_32x32x16_bf16(V0, fA0, oaccA, 0, 0, 0);       \
    oaccA = __builtin_amdgcn_mfma_f32_32x32x16_bf16(V1, fA1, oaccA, 0, 0, 0);       \
    oaccB = __builtin_amdgcn_mfma_f32_32x32x16_bf16(V0, fB0, oaccB, 0, 0, 0);       \
    oaccB = __builtin_amdgcn_mfma_f32_32x32x16_bf16(V1, fB1, oaccB, 0, 0, 0);       \
    V0 = *(const short8*)(Vc + (NX) * 1024 + lofs);                                 \
    V1 = *(const short8*)(Vc + (NX) * 1024 + 512 + lofs);                           \
  }

  for (int it = 0; it < 32; it += 2) {
    FSTEP(kA0, kA1, vA0, vA1, (it + 2) & 31);
    FSTEP(kB0, kB1, vB0, vB1, (it + 3) & 31);
  }
#undef FSTEP

  // cross-half l sums
  {
    float a = lA, b = lA;
    asm("v_permlane32_swap_b32 %0, %1" : "+v"(a), "+v"(b));
    lA = a + b;
    float c = lB, d = lB;
    asm("v_permlane32_swap_b32 %0, %1" : "+v"(c), "+v"(d));
    lB = c + d;
  }

  // ---- cross-wave combine via LDS (plain sums), then restage for row-major write ----
  __shared__ float lsbuf[2 * NSPLIT * 16 * 64];   // 32KB, reused in two phases
  __shared__ float lm[2][NSPLIT][32];
#pragma unroll
  for (int r = 0; r < 16; ++r) {
    lsbuf[((0 * NSPLIT + w) * 16 + r) * 64 + lane] = oaccA[r];
    lsbuf[((1 * NSPLIT + w) * 16 + r) * 64 + lane] = oaccB[r];
  }
  if (!hi) { lm[0][w][l31] = lA; lm[1][w][l31] = lB; }
  __syncthreads();

  float LA = (lm[0][0][l31] + lm[0][1][l31]) + (lm[0][2][l31] + lm[0][3][l31]);
  float LB = (lm[1][0][l31] + lm[1][1][l31]) + (lm[1][2][l31] + lm[1][3][l31]);
  float invLA = 1.0f / LA, invLB = 1.0f / LB;
  float va4[4], vb4[4];
#pragma unroll
  for (int rr = 0; rr < 4; ++rr) {
    int r = w * 4 + rr;
    float va = 0.f, vb = 0.f;
#pragma unroll
    for (int i = 0; i < NSPLIT; ++i) {
      va += lsbuf[((0 * NSPLIT + i) * 16 + r) * 64 + lane];
      vb += lsbuf[((1 * NSPLIT + i) * 16 + r) * 64 + lane];
    }
    va4[rr] = va * invLA;
    vb4[rr] = vb * invLB;
  }
  __syncthreads();
#pragma unroll
  for (int rr = 0; rr < 4; ++rr) {
    int r = w * 4 + rr;
    int d = (r & 3) + 8 * (r >> 2) + 4 * hi;
    lsbuf[l31 * 33 + d]        = va4[rr];
    lsbuf[(32 + l31) * 33 + d] = vb4[rr];
  }
  __syncthreads();
  {
    int bb = bh >> 3, hh = bh & 7;
    int t = threadIdx.x;
    int qq = t >> 2, dg = (t & 3) * 8;
    union { unsigned short us[8]; short8 s8; } pk;
#pragma unroll
    for (int e = 0; e < 8; ++e) pk.us[e] = f2bu(lsbuf[qq * 33 + dg + e]);
    *(short8*)(of + ((size_t)bb * Sn + q0 + qq) * Cdim + hh * Dh + dg) = pk.s8;
  }
}

// ---------------- output projection + residual: of [B*S,C] row-major ----
__global__ void k_oproj(const unsigned short* __restrict__ of, const unsigned short* __restrict__ wo,
                        const float* __restrict__ bo, const float* __restrict__ x,
                        float* __restrict__ out) {
  int w = threadIdx.x >> 6, lane = threadIdx.x & 63;
  int lr = lane & 15, lg = lane >> 4;
  int m0 = blockIdx.x * 64 + w * 16;
  int n0 = blockIdx.y * 64;
  floatx4 acc[4] = {};
  for (int k0 = 0; k0 < 256; k0 += 32) {
    short8 a = *(const short8*)(of + (size_t)(m0 + lr) * 256 + k0 + lg * 8);
#pragma unroll
    for (int nt = 0; nt < 4; ++nt) {
      short8 bfr = *(const short8*)(wo + (size_t)(n0 + nt * 16 + lr) * 256 + k0 + lg * 8);
      acc[nt] = __builtin_amdgcn_mfma_f32_16x16x32_bf16(a, bfr, acc[nt], 0, 0, 0);
    }
  }
  __shared__ float tl[64][65];
#pragma unroll
  for (int nt = 0; nt < 4; ++nt) {
    float bias = bo[n0 + nt * 16 + lr];
#pragma unroll
    for (int j = 0; j < 4; ++j)
      tl[w * 16 + lg * 4 + j][nt * 16 + lr] = acc[nt][j] + bias;
  }
  __syncthreads();
  int mBase = blockIdx.x * 64;
#pragma unroll
  for (int i = 0; i < 16; ++i) {
    int cl = i * 4 + (threadIdx.x >> 6);
    int ml = threadIdx.x & 63;
    int m = mBase + ml;
    int bb = m >> 12, s = m & 4095;
    size_t oi = ((size_t)(bb * Cdim + n0 + cl)) * Sn + s;
    out[oi] = tl[ml][cl] + x[oi];
  }
}

extern "C" void kernel_launch(void* const* d_in, const int* in_sizes, int n_in,
                              void* d_out, int out_size, void* d_ws, size_t ws_size,
                              hipStream_t stream) {
  const float* x  = (const float*)d_in[0];
  const float* gw = (const float*)d_in[1];
  const float* gb = (const float*)d_in[2];
  const float* Wq = (const float*)d_in[3];
  const float* bq = (const float*)d_in[4];
  const float* Wk = (const float*)d_in[5];
  const float* bk = (const float*)d_in[6];
  const float* Wv = (const float*)d_in[7];
  const float* bv = (const float*)d_in[8];
  const float* Wo = (const float*)d_in[9];
  const float* bo = (const float*)d_in[10];
  float* out = (float*)d_out;
  char* ws = (char*)d_ws;
  if (ws_size < 0x1482000) return;  // need ~20.5 MB scratch

  float* part  = (float*)(ws);              // 512*2 f32
  unsigned short* wall = (unsigned short*)(ws + 0x2000);    // 4 x 256x256 bf16
  unsigned short* qf   = (unsigned short*)(ws + 0x482000);  // [B,H,S,32] bf16 (scaled, log2e folded)
  unsigned short* kswz = (unsigned short*)(ws + 0x882000);  // fragment-major K
  unsigned short* vswz = (unsigned short*)(ws + 0xC82000);  // fragment-major V^T
  unsigned short* of   = (unsigned short*)(ws + 0x1082000); // [B*S, C] bf16 row-major

  hipLaunchKernelGGL(k_pre, dim3(768), dim3(256), 0, stream, x, Wq, Wk, Wv, Wo, part, wall);
  hipLaunchKernelGGL(k_nqkv, dim3(128, 6), dim3(256), 0, stream, x, gw, gb, part, wall,
                     bq, bk, bv, qf, kswz, vswz);
  hipLaunchKernelGGL(k_flash, dim3(1024), dim3(256), 0, stream, qf, kswz, vswz, of);
  hipLaunchKernelGGL(k_oproj, dim3(128, 4), dim3(256), 0, stream, of, wall + 3 * 65536, bo, x, out);
}

// Round 15
// 100.594 us; speedup vs baseline: 1.4071x; 1.4071x over previous
//
#include <hip/hip_runtime.h>
#include <hip/hip_bf16.h>
#include <math.h>

#define Cdim 256
#define Hn 8
#define Bn 2
#define Sn 4096
#define Dh 32
#define GN_EPS 1e-5f
#define QK_SCALE 0.42044820762685725f   // 32^(-1/4), applied to BOTH q and k like the reference
#define LOG2E 1.4426950408889634f
#define NSPLIT 4
#define BHSZ (Sn * Dh)                  // elems per (b,h) in swizzled K/V
#define HLP 264                         // hl pitch in shorts (16B-aligned rows)

typedef __attribute__((ext_vector_type(8))) short short8;
typedef __attribute__((ext_vector_type(4))) float floatx4;
typedef __attribute__((ext_vector_type(16))) float floatx16;

__device__ __forceinline__ unsigned short f2bu(float x) {
  union { float f; unsigned u; } v; v.f = x;
  unsigned r = v.u + 0x7fffu + ((v.u >> 16) & 1u);  // RNE
  return (unsigned short)(r >> 16);
}

// pack 16 f32 probs -> two bf16x8 B-fragments via cvt_pk + permlane32_swap (T12)
__device__ __forceinline__ void pack_pt(const floatx16& p, short8& f0, short8& f1) {
  unsigned c0, c1, c2, c3, c4, c5, c6, c7;
  asm("v_cvt_pk_bf16_f32 %0, %1, %2" : "=v"(c0) : "v"(p[0]),  "v"(p[1]));
  asm("v_cvt_pk_bf16_f32 %0, %1, %2" : "=v"(c1) : "v"(p[2]),  "v"(p[3]));
  asm("v_cvt_pk_bf16_f32 %0, %1, %2" : "=v"(c2) : "v"(p[4]),  "v"(p[5]));
  asm("v_cvt_pk_bf16_f32 %0, %1, %2" : "=v"(c3) : "v"(p[6]),  "v"(p[7]));
  asm("v_cvt_pk_bf16_f32 %0, %1, %2" : "=v"(c4) : "v"(p[8]),  "v"(p[9]));
  asm("v_cvt_pk_bf16_f32 %0, %1, %2" : "=v"(c5) : "v"(p[10]), "v"(p[11]));
  asm("v_cvt_pk_bf16_f32 %0, %1, %2" : "=v"(c6) : "v"(p[12]), "v"(p[13]));
  asm("v_cvt_pk_bf16_f32 %0, %1, %2" : "=v"(c7) : "v"(p[14]), "v"(p[15]));
  asm("v_permlane32_swap_b32 %0, %1" : "+v"(c0), "+v"(c2));
  asm("v_permlane32_swap_b32 %0, %1" : "+v"(c1), "+v"(c3));
  asm("v_permlane32_swap_b32 %0, %1" : "+v"(c4), "+v"(c6));
  asm("v_permlane32_swap_b32 %0, %1" : "+v"(c5), "+v"(c7));
  union { unsigned u[4]; short8 s8; } a, b;
  a.u[0] = c0; a.u[1] = c1; a.u[2] = c2; a.u[3] = c3;
  b.u[0] = c4; b.u[1] = c5; b.u[2] = c6; b.u[3] = c7;
  f0 = a.s8; f1 = b.s8;
}

// ---------------- fused: GroupNorm partial stats (blocks 0-511) + weight cast (512-767) ----
__global__ void k_pre(const float* __restrict__ x,
                      const float* __restrict__ wq, const float* __restrict__ wk,
                      const float* __restrict__ wv, const float* __restrict__ wo,
                      float* __restrict__ part, unsigned short* __restrict__ wall) {
  if (blockIdx.x < 512) {
    int b = blockIdx.x >> 8;
    int base = (blockIdx.x & 255) * 4096 + b * (Cdim * Sn);
    float s = 0.f, ss = 0.f;
#pragma unroll
    for (int k = 0; k < 16; ++k) {
      float v = x[base + k * 256 + threadIdx.x];
      s += v; ss += v * v;
    }
    for (int off = 32; off; off >>= 1) { s += __shfl_down(s, off); ss += __shfl_down(ss, off); }
    __shared__ float as[4], bs[4];
    int w = threadIdx.x >> 6;
    if ((threadIdx.x & 63) == 0) { as[w] = s; bs[w] = ss; }
    __syncthreads();
    if (threadIdx.x == 0) {
      part[blockIdx.x * 2]     = as[0] + as[1] + as[2] + as[3];
      part[blockIdx.x * 2 + 1] = bs[0] + bs[1] + bs[2] + bs[3];
    }
  } else {
    int i = (blockIdx.x - 512) * 256 + threadIdx.x;  // 65536 total
    wall[0 * 65536 + i] = f2bu(wq[i]);
    wall[1 * 65536 + i] = f2bu(wk[i]);
    wall[2 * 65536 + i] = f2bu(wv[i]);
    wall[3 * 65536 + i] = f2bu(wo[i]);
  }
}

// ---------------- fused GroupNorm + QKV projection (R12, unchanged) ----------------
__global__ void k_nqkv(const float* __restrict__ x, const float* __restrict__ gw,
                       const float* __restrict__ gb, const float* __restrict__ part,
                       const unsigned short* __restrict__ wall,
                       const float* __restrict__ bq, const float* __restrict__ bk,
                       const float* __restrict__ bv,
                       unsigned short* __restrict__ qf, unsigned short* __restrict__ kswz,
                       unsigned short* __restrict__ vswz) {
  int sb = blockIdx.x;                  // 0..127, rows mBase..mBase+63
  int mBase = sb * 64;
  int b = sb >> 6;
  int proj = blockIdx.y >> 1, half = blockIdx.y & 1;
  int w = threadIdx.x >> 6, lane = threadIdx.x & 63;
  int lr = lane & 15, lg = lane >> 4;

  __shared__ float as[4], bs[4];
  {
    float s  = part[(b * 256 + threadIdx.x) * 2];
    float ss = part[(b * 256 + threadIdx.x) * 2 + 1];
    for (int off = 32; off; off >>= 1) { s += __shfl_down(s, off); ss += __shfl_down(ss, off); }
    if ((threadIdx.x & 63) == 0) { as[w] = s; bs[w] = ss; }
  }
  __syncthreads();
  const float invN = 1.f / (float)(Cdim * Sn);
  float mean = (as[0] + as[1] + as[2] + as[3]) * invN;
  float var  = (bs[0] + bs[1] + bs[2] + bs[3]) * invN - mean * mean;
  float rstd = rsqrtf(var + GN_EPS);

  __shared__ unsigned short hl[64][HLP];
  {
    int s0 = mBase & 4095;
    int rg = threadIdx.x >> 6;
#pragma unroll
    for (int i = 0; i < 32; ++i) {
      int cl = i * 8 + rg * 2;
      float v0 = x[((size_t)(b * Cdim + cl))     * Sn + s0 + lane];
      float v1 = x[((size_t)(b * Cdim + cl + 1)) * Sn + s0 + lane];
      float y0 = (v0 - mean) * rstd * gw[cl]     + gb[cl];
      float y1 = (v1 - mean) * rstd * gw[cl + 1] + gb[cl + 1];
      unsigned pkv = (unsigned)f2bu(y0) | ((unsigned)f2bu(y1) << 16);
      *(unsigned*)&hl[lane][cl] = pkv;
    }
  }
  __syncthreads();

  const unsigned short* W = wall + proj * 65536;
  __shared__ float tl[64][65];
  for (int sub = 0; sub < 2; ++sub) {
    int n0 = half * 128 + sub * 64;
    floatx4 acc[4] = {};
    for (int k0 = 0; k0 < 256; k0 += 32) {
      short8 a = *(const short8*)&hl[w * 16 + lr][k0 + lg * 8];
#pragma unroll
      for (int nt = 0; nt < 4; ++nt) {
        short8 bfr = *(const short8*)(W + (size_t)(n0 + nt * 16 + lr) * 256 + k0 + lg * 8);
        acc[nt] = __builtin_amdgcn_mfma_f32_16x16x32_bf16(a, bfr, acc[nt], 0, 0, 0);
      }
    }
    if (sub) __syncthreads();
    {
      const float* bias = (proj == 0) ? bq : (proj == 1 ? bk : bv);
      float scale = (proj == 0) ? (QK_SCALE * LOG2E) : (proj == 1 ? QK_SCALE : 1.f);
#pragma unroll
      for (int nt = 0; nt < 4; ++nt) {
        int nl = nt * 16 + lr;
        float bias_n = bias[n0 + nl];
#pragma unroll
        for (int j = 0; j < 4; ++j)
          tl[nl][w * 16 + lg * 4 + j] = (acc[nt][j] + bias_n) * scale;
      }
    }
    __syncthreads();
    if (proj < 2) {
#pragma unroll
      for (int i = 0; i < 2; ++i) {
        int t = threadIdx.x + 256 * i;
        int s_l = t & 63, oct = t >> 6;
        int m = mBase + s_l, bb = m >> 12, s = m & 4095;
        int cp = n0 + oct * 8;
        int hh = cp >> 5, dd0 = cp & 31;
        int bh = bb * Hn + hh;
        union { unsigned short us[8]; short8 s8; } pk;
#pragma unroll
        for (int e = 0; e < 8; ++e) pk.us[e] = f2bu(tl[oct * 8 + e][s_l]);
        if (proj == 0) {
          *(short8*)(qf + ((size_t)bh * Sn + s) * Dh + dd0) = pk.s8;
        } else {
          int fr = dd0 >> 4, ddl = (dd0 >> 3) & 1;
          size_t off = (size_t)bh * BHSZ +
                       (size_t)(((((s >> 5) * 2 + fr) * 64) + (s & 31) + 32 * ddl) * 8);
          *(short8*)(kswz + off) = pk.s8;
        }
      }
    } else {
#pragma unroll
      for (int i = 0; i < 2; ++i) {
        int t = threadIdx.x + 256 * i;
        int dd_l = t & 63, soct = t >> 6;
        int cp = n0 + dd_l;
        int hh = cp >> 5, dd = cp & 31;
        int m = mBase + soct * 8, bb = m >> 12, s = m & 4095;
        int bh = bb * Hn + hh;
        union { unsigned short us[8]; short8 s8; } pk;
#pragma unroll
        for (int e = 0; e < 8; ++e) pk.us[e] = f2bu(tl[dd_l][soct * 8 + e]);
        size_t off = (size_t)bh * BHSZ +
                     (size_t)(((((s >> 5) * 2 + ((s >> 4) & 1)) * 64) + dd + 32 * ((s >> 3) & 1)) * 8);
        *(short8*)(vswz + off) = pk.s8;
      }
    }
  }
}

// ---------------- flash attention: 64q/wave, split-K x4, fragment-major K/V ----------
// R12/R10 proven body with ONE change: s_setprio removed (T5/m190: setprio on uniform
// barrier-less waves causes a convoy effect — one wave's prio-1 MFMA cluster starves
// co-resident waves' exp issue). Depth-1 prefetch only (R14: depth-2 spills, 103MB scratch).
__global__ __launch_bounds__(256, 4) void k_flash(
    const unsigned short* __restrict__ qf, const unsigned short* __restrict__ kswz,
    const unsigned short* __restrict__ vswz, unsigned short* __restrict__ of) {
  int w = threadIdx.x >> 6, lane = threadIdx.x & 63;
  int l31 = lane & 31, hi = lane >> 5;
  int lin = blockIdx.x;                                // 0..1023
  int xcd = lin & 7, slot = lin >> 3;                  // 128 slots per XCD
  int bh = xcd + 8 * (slot >> 6);                      // 2 bh per XCD
  int q0 = (slot & 63) * 64;
  const unsigned short* Q = qf + (size_t)bh * Sn * Dh;

  short8 qa0 = *(const short8*)(Q + (size_t)(q0 + l31) * Dh + hi * 8);
  short8 qa1 = *(const short8*)(Q + (size_t)(q0 + l31) * Dh + 16 + hi * 8);
  short8 qc0 = *(const short8*)(Q + (size_t)(q0 + 32 + l31) * Dh + hi * 8);
  short8 qc1 = *(const short8*)(Q + (size_t)(q0 + 32 + l31) * Dh + 16 + hi * 8);

  floatx16 oaccA = {}, oaccB = {};  // O^T[d][q]: col q = l31, row d = (r&3)+8*(r>>2)+4*hi
  float lA = 0.f, lB = 0.f;
  const floatx16 zero16 = {};
  const unsigned short* Kc = kswz + (size_t)bh * BHSZ + (size_t)(w * 32) * 1024;
  const unsigned short* Vc = vswz + (size_t)bh * BHSZ + (size_t)(w * 32) * 1024;
  const int lofs = lane * 8;

  short8 kb0 = *(const short8*)(Kc + lofs);
  short8 kb1 = *(const short8*)(Kc + 512 + lofs);
  short8 vb0 = *(const short8*)(Vc + lofs);
  short8 vb1 = *(const short8*)(Vc + 512 + lofs);

  for (int it = 0; it < 32; ++it) {
    floatx16 sA = __builtin_amdgcn_mfma_f32_32x32x16_bf16(kb0, qa0, zero16, 0, 0, 0);
    sA = __builtin_amdgcn_mfma_f32_32x32x16_bf16(kb1, qa1, sA, 0, 0, 0);
    floatx16 sB = __builtin_amdgcn_mfma_f32_32x32x16_bf16(kb0, qc0, zero16, 0, 0, 0);
    sB = __builtin_amdgcn_mfma_f32_32x32x16_bf16(kb1, qc1, sB, 0, 0, 0);

    int nx = (it + 1) & 31;
    short8 nkb0 = *(const short8*)(Kc + nx * 1024 + lofs);
    short8 nkb1 = *(const short8*)(Kc + nx * 1024 + 512 + lofs);
    short8 nvb0 = *(const short8*)(Vc + nx * 1024 + lofs);
    short8 nvb1 = *(const short8*)(Vc + nx * 1024 + 512 + lofs);

#pragma unroll
    for (int i = 0; i < 16; ++i) sA[i] = __builtin_amdgcn_exp2f(sA[i]);
#pragma unroll
    for (int i = 0; i < 16; ++i) sB[i] = __builtin_amdgcn_exp2f(sB[i]);

    {
      float t0 = (sA[0] + sA[1]) + (sA[2] + sA[3]);
      float t1 = (sA[4] + sA[5]) + (sA[6] + sA[7]);
      float t2 = (sA[8] + sA[9]) + (sA[10] + sA[11]);
      float t3 = (sA[12] + sA[13]) + (sA[14] + sA[15]);
      lA += (t0 + t1) + (t2 + t3);
      float u0 = (sB[0] + sB[1]) + (sB[2] + sB[3]);
      float u1 = (sB[4] + sB[5]) + (sB[6] + sB[7]);
      float u2 = (sB[8] + sB[9]) + (sB[10] + sB[11]);
      float u3 = (sB[12] + sB[13]) + (sB[14] + sB[15]);
      lB += (u0 + u1) + (u2 + u3);
    }

    short8 fA0, fA1, fB0, fB1;
    pack_pt(sA, fA0, fA1);
    pack_pt(sB, fB0, fB1);

    oaccA = __builtin_amdgcn_mfma_f32_32x32x16_bf16(vb0, fA0, oaccA, 0, 0, 0);
    oaccA = __builtin_amdgcn_mfma_f32_32x32x16_bf16(vb1, fA1, oaccA, 0, 0, 0);
    oaccB = __builtin_amdgcn_mfma_f32_32x32x16_bf16(vb0, fB0, oaccB, 0, 0, 0);
    oaccB = __builtin_amdgcn_mfma_f32_32x32x16_bf16(vb1, fB1, oaccB, 0, 0, 0);

    kb0 = nkb0; kb1 = nkb1; vb0 = nvb0; vb1 = nvb1;
  }

  // cross-half l sums
  {
    float a = lA, b = lA;
    asm("v_permlane32_swap_b32 %0, %1" : "+v"(a), "+v"(b));
    lA = a + b;
    float c = lB, d = lB;
    asm("v_permlane32_swap_b32 %0, %1" : "+v"(c), "+v"(d));
    lB = c + d;
  }

  // ---- cross-wave combine via LDS (plain sums), then restage for row-major write ----
  __shared__ float lsbuf[2 * NSPLIT * 16 * 64];   // 32KB, reused in two phases
  __shared__ float lm[2][NSPLIT][32];
#pragma unroll
  for (int r = 0; r < 16; ++r) {
    lsbuf[((0 * NSPLIT + w) * 16 + r) * 64 + lane] = oaccA[r];
    lsbuf[((1 * NSPLIT + w) * 16 + r) * 64 + lane] = oaccB[r];
  }
  if (!hi) { lm[0][w][l31] = lA; lm[1][w][l31] = lB; }
  __syncthreads();

  float LA = (lm[0][0][l31] + lm[0][1][l31]) + (lm[0][2][l31] + lm[0][3][l31]);
  float LB = (lm[1][0][l31] + lm[1][1][l31]) + (lm[1][2][l31] + lm[1][3][l31]);
  float invLA = 1.0f / LA, invLB = 1.0f / LB;
  float va4[4], vb4[4];
#pragma unroll
  for (int rr = 0; rr < 4; ++rr) {
    int r = w * 4 + rr;
    float va = 0.f, vb = 0.f;
#pragma unroll
    for (int i = 0; i < NSPLIT; ++i) {
      va += lsbuf[((0 * NSPLIT + i) * 16 + r) * 64 + lane];
      vb += lsbuf[((1 * NSPLIT + i) * 16 + r) * 64 + lane];
    }
    va4[rr] = va * invLA;
    vb4[rr] = vb * invLB;
  }
  __syncthreads();
#pragma unroll
  for (int rr = 0; rr < 4; ++rr) {
    int r = w * 4 + rr;
    int d = (r & 3) + 8 * (r >> 2) + 4 * hi;
    lsbuf[l31 * 33 + d]        = va4[rr];
    lsbuf[(32 + l31) * 33 + d] = vb4[rr];
  }
  __syncthreads();
  {
    int bb = bh >> 3, hh = bh & 7;
    int t = threadIdx.x;
    int qq = t >> 2, dg = (t & 3) * 8;
    union { unsigned short us[8]; short8 s8; } pk;
#pragma unroll
    for (int e = 0; e < 8; ++e) pk.us[e] = f2bu(lsbuf[qq * 33 + dg + e]);
    *(short8*)(of + ((size_t)bb * Sn + q0 + qq) * Cdim + hh * Dh + dg) = pk.s8;
  }
}

// ---------------- output projection + residual: of [B*S,C] row-major ----
__global__ void k_oproj(const unsigned short* __restrict__ of, const unsigned short* __restrict__ wo,
                        const float* __restrict__ bo, const float* __restrict__ x,
                        float* __restrict__ out) {
  int w = threadIdx.x >> 6, lane = threadIdx.x & 63;
  int lr = lane & 15, lg = lane >> 4;
  int m0 = blockIdx.x * 64 + w * 16;
  int n0 = blockIdx.y * 64;
  floatx4 acc[4] = {};
  for (int k0 = 0; k0 < 256; k0 += 32) {
    short8 a = *(const short8*)(of + (size_t)(m0 + lr) * 256 + k0 + lg * 8);
#pragma unroll
    for (int nt = 0; nt < 4; ++nt) {
      short8 bfr = *(const short8*)(wo + (size_t)(n0 + nt * 16 + lr) * 256 + k0 + lg * 8);
      acc[nt] = __builtin_amdgcn_mfma_f32_16x16x32_bf16(a, bfr, acc[nt], 0, 0, 0);
    }
  }
  __shared__ float tl[64][65];
#pragma unroll
  for (int nt = 0; nt < 4; ++nt) {
    float bias = bo[n0 + nt * 16 + lr];
#pragma unroll
    for (int j = 0; j < 4; ++j)
      tl[w * 16 + lg * 4 + j][nt * 16 + lr] = acc[nt][j] + bias;
  }
  __syncthreads();
  int mBase = blockIdx.x * 64;
#pragma unroll
  for (int i = 0; i < 16; ++i) {
    int cl = i * 4 + (threadIdx.x >> 6);
    int ml = threadIdx.x & 63;
    int m = mBase + ml;
    int bb = m >> 12, s = m & 4095;
    size_t oi = ((size_t)(bb * Cdim + n0 + cl)) * Sn + s;
    out[oi] = tl[ml][cl] + x[oi];
  }
}

extern "C" void kernel_launch(void* const* d_in, const int* in_sizes, int n_in,
                              void* d_out, int out_size, void* d_ws, size_t ws_size,
                              hipStream_t stream) {
  const float* x  = (const float*)d_in[0];
  const float* gw = (const float*)d_in[1];
  const float* gb = (const float*)d_in[2];
  const float* Wq = (const float*)d_in[3];
  const float* bq = (const float*)d_in[4];
  const float* Wk = (const float*)d_in[5];
  const float* bk = (const float*)d_in[6];
  const float* Wv = (const float*)d_in[7];
  const float* bv = (const float*)d_in[8];
  const float* Wo = (const float*)d_in[9];
  const float* bo = (const float*)d_in[10];
  float* out = (float*)d_out;
  char* ws = (char*)d_ws;
  if (ws_size < 0x1482000) return;  // need ~20.5 MB scratch

  float* part  = (float*)(ws);              // 512*2 f32
  unsigned short* wall = (unsigned short*)(ws + 0x2000);    // 4 x 256x256 bf16
  unsigned short* qf   = (unsigned short*)(ws + 0x482000);  // [B,H,S,32] bf16 (scaled, log2e folded)
  unsigned short* kswz = (unsigned short*)(ws + 0x882000);  // fragment-major K
  unsigned short* vswz = (unsigned short*)(ws + 0xC82000);  // fragment-major V^T
  unsigned short* of   = (unsigned short*)(ws + 0x1082000); // [B*S, C] bf16 row-major

  hipLaunchKernelGGL(k_pre, dim3(768), dim3(256), 0, stream, x, Wq, Wk, Wv, Wo, part, wall);
  hipLaunchKernelGGL(k_nqkv, dim3(128, 6), dim3(256), 0, stream, x, gw, gb, part, wall,
                     bq, bk, bv, qf, kswz, vswz);
  hipLaunchKernelGGL(k_flash, dim3(1024), dim3(256), 0, stream, qf, kswz, vswz, of);
  hipLaunchKernelGGL(k_oproj, dim3(128, 4), dim3(256), 0, stream, of, wall + 3 * 65536, bo, x, out);
}

// Round 16
// 81.209 us; speedup vs baseline: 1.7430x; 1.2387x over previous
//
#include <hip/hip_runtime.h>
#include <hip/hip_bf16.h>
#include <math.h>

#define Cdim 256
#define Hn 8
#define Bn 2
#define Sn 4096
#define Dh 32
#define GN_EPS 1e-5f
#define QK_SCALE 0.42044820762685725f   // 32^(-1/4), applied to BOTH q and k like the reference
#define LOG2E 1.4426950408889634f
#define NSPLIT 4
#define BHSZ (Sn * Dh)                  // elems per (b,h) in swizzled K/V
#define HLP 264                         // hl pitch in shorts (16B-aligned rows)

typedef __attribute__((ext_vector_type(8))) short short8;
typedef __attribute__((ext_vector_type(4))) float floatx4;
typedef __attribute__((ext_vector_type(16))) float floatx16;

__device__ __forceinline__ unsigned short f2bu(float x) {
  union { float f; unsigned u; } v; v.f = x;
  unsigned r = v.u + 0x7fffu + ((v.u >> 16) & 1u);  // RNE
  return (unsigned short)(r >> 16);
}

// pack 16 f32 probs -> two bf16x8 B-fragments via cvt_pk + permlane32_swap (T12)
__device__ __forceinline__ void pack_pt(const floatx16& p, short8& f0, short8& f1) {
  unsigned c0, c1, c2, c3, c4, c5, c6, c7;
  asm("v_cvt_pk_bf16_f32 %0, %1, %2" : "=v"(c0) : "v"(p[0]),  "v"(p[1]));
  asm("v_cvt_pk_bf16_f32 %0, %1, %2" : "=v"(c1) : "v"(p[2]),  "v"(p[3]));
  asm("v_cvt_pk_bf16_f32 %0, %1, %2" : "=v"(c2) : "v"(p[4]),  "v"(p[5]));
  asm("v_cvt_pk_bf16_f32 %0, %1, %2" : "=v"(c3) : "v"(p[6]),  "v"(p[7]));
  asm("v_cvt_pk_bf16_f32 %0, %1, %2" : "=v"(c4) : "v"(p[8]),  "v"(p[9]));
  asm("v_cvt_pk_bf16_f32 %0, %1, %2" : "=v"(c5) : "v"(p[10]), "v"(p[11]));
  asm("v_cvt_pk_bf16_f32 %0, %1, %2" : "=v"(c6) : "v"(p[12]), "v"(p[13]));
  asm("v_cvt_pk_bf16_f32 %0, %1, %2" : "=v"(c7) : "v"(p[14]), "v"(p[15]));
  asm("v_permlane32_swap_b32 %0, %1" : "+v"(c0), "+v"(c2));
  asm("v_permlane32_swap_b32 %0, %1" : "+v"(c1), "+v"(c3));
  asm("v_permlane32_swap_b32 %0, %1" : "+v"(c4), "+v"(c6));
  asm("v_permlane32_swap_b32 %0, %1" : "+v"(c5), "+v"(c7));
  union { unsigned u[4]; short8 s8; } a, b;
  a.u[0] = c0; a.u[1] = c1; a.u[2] = c2; a.u[3] = c3;
  b.u[0] = c4; b.u[1] = c5; b.u[2] = c6; b.u[3] = c7;
  f0 = a.s8; f1 = b.s8;
}

// ---------------- fused: GroupNorm partial stats (blocks 0-511) + weight cast+swizzle ----
// Weights written in B-FRAGMENT-MAJOR bf16: for W[n][k] (256x256),
//   off = ((n>>4)*8 + (k>>5))*512 + ((n&15) + 16*((k>>3)&3))*8 + (k&7)
// so a GEMM B-load is base + frag*512 + lane*8 (one coalesced dwordx4 per wave).
__global__ void k_pre(const float* __restrict__ x,
                      const float* __restrict__ wq, const float* __restrict__ wk,
                      const float* __restrict__ wv, const float* __restrict__ wo,
                      float* __restrict__ part, unsigned short* __restrict__ wall) {
  if (blockIdx.x < 512) {
    int b = blockIdx.x >> 8;
    int base = (blockIdx.x & 255) * 4096 + b * (Cdim * Sn);
    float s = 0.f, ss = 0.f;
#pragma unroll
    for (int k = 0; k < 16; ++k) {
      float v = x[base + k * 256 + threadIdx.x];
      s += v; ss += v * v;
    }
    for (int off = 32; off; off >>= 1) { s += __shfl_down(s, off); ss += __shfl_down(ss, off); }
    __shared__ float as[4], bs[4];
    int w = threadIdx.x >> 6;
    if ((threadIdx.x & 63) == 0) { as[w] = s; bs[w] = ss; }
    __syncthreads();
    if (threadIdx.x == 0) {
      part[blockIdx.x * 2]     = as[0] + as[1] + as[2] + as[3];
      part[blockIdx.x * 2 + 1] = bs[0] + bs[1] + bs[2] + bs[3];
    }
  } else {
    // 128 blocks x 256 threads = 32768 threads; one short8 (8 consecutive k) each
    int tid = (blockIdx.x - 512) * 256 + threadIdx.x;   // 0..32767
    int mat = tid >> 13;                                 // 0..3
    int idx = tid & 8191;                                // 0..8191 (short8 id)
    int n = idx >> 5, k8 = (idx & 31) * 8;
    const float* src = (mat == 0) ? wq : (mat == 1) ? wk : (mat == 2) ? wv : wo;
    union { unsigned short us[8]; short8 s8; } pk;
#pragma unroll
    for (int e = 0; e < 8; ++e) pk.us[e] = f2bu(src[n * 256 + k8 + e]);
    size_t off = (size_t)mat * 65536 +
                 (size_t)((((n >> 4) * 8 + (k8 >> 5)) * 512) + ((n & 15) + 16 * ((k8 >> 3) & 3)) * 8);
    *(short8*)(wall + off) = pk.s8;
  }
}

// ---------------- fused GroupNorm + QKV projection (frag-major W reads) ----------------
__global__ void k_nqkv(const float* __restrict__ x, const float* __restrict__ gw,
                       const float* __restrict__ gb, const float* __restrict__ part,
                       const unsigned short* __restrict__ wall,
                       const float* __restrict__ bq, const float* __restrict__ bk,
                       const float* __restrict__ bv,
                       unsigned short* __restrict__ qf, unsigned short* __restrict__ kswz,
                       unsigned short* __restrict__ vswz) {
  int sb = blockIdx.x;                  // 0..127, rows mBase..mBase+63
  int mBase = sb * 64;
  int b = sb >> 6;
  int proj = blockIdx.y >> 1, half = blockIdx.y & 1;
  int w = threadIdx.x >> 6, lane = threadIdx.x & 63;
  int lr = lane & 15, lg = lane >> 4;

  __shared__ float as[4], bs[4];
  {
    float s  = part[(b * 256 + threadIdx.x) * 2];
    float ss = part[(b * 256 + threadIdx.x) * 2 + 1];
    for (int off = 32; off; off >>= 1) { s += __shfl_down(s, off); ss += __shfl_down(ss, off); }
    if ((threadIdx.x & 63) == 0) { as[w] = s; bs[w] = ss; }
  }
  __syncthreads();
  const float invN = 1.f / (float)(Cdim * Sn);
  float mean = (as[0] + as[1] + as[2] + as[3]) * invN;
  float var  = (bs[0] + bs[1] + bs[2] + bs[3]) * invN - mean * mean;
  float rstd = rsqrtf(var + GN_EPS);

  __shared__ unsigned short hl[64][HLP];
  {
    int s0 = mBase & 4095;
    int rg = threadIdx.x >> 6;
#pragma unroll
    for (int i = 0; i < 32; ++i) {
      int cl = i * 8 + rg * 2;
      float v0 = x[((size_t)(b * Cdim + cl))     * Sn + s0 + lane];
      float v1 = x[((size_t)(b * Cdim + cl + 1)) * Sn + s0 + lane];
      float y0 = (v0 - mean) * rstd * gw[cl]     + gb[cl];
      float y1 = (v1 - mean) * rstd * gw[cl + 1] + gb[cl + 1];
      unsigned pkv = (unsigned)f2bu(y0) | ((unsigned)f2bu(y1) << 16);
      *(unsigned*)&hl[lane][cl] = pkv;
    }
  }
  __syncthreads();

  const unsigned short* W = wall + proj * 65536;
  __shared__ float tl[64][65];
  for (int sub = 0; sub < 2; ++sub) {
    int n0 = half * 128 + sub * 64;
    floatx4 acc[4] = {};
    for (int k0 = 0; k0 < 256; k0 += 32) {
      short8 a = *(const short8*)&hl[w * 16 + lr][k0 + lg * 8];
#pragma unroll
      for (int nt = 0; nt < 4; ++nt) {
        short8 bfr = *(const short8*)(W + (size_t)((((n0 >> 4) + nt) * 8 + (k0 >> 5)) * 512 + lane * 8));
        acc[nt] = __builtin_amdgcn_mfma_f32_16x16x32_bf16(a, bfr, acc[nt], 0, 0, 0);
      }
    }
    if (sub) __syncthreads();
    {
      const float* bias = (proj == 0) ? bq : (proj == 1 ? bk : bv);
      float scale = (proj == 0) ? (QK_SCALE * LOG2E) : (proj == 1 ? QK_SCALE : 1.f);
#pragma unroll
      for (int nt = 0; nt < 4; ++nt) {
        int nl = nt * 16 + lr;
        float bias_n = bias[n0 + nl];
#pragma unroll
        for (int j = 0; j < 4; ++j)
          tl[nl][w * 16 + lg * 4 + j] = (acc[nt][j] + bias_n) * scale;
      }
    }
    __syncthreads();
    if (proj < 2) {
#pragma unroll
      for (int i = 0; i < 2; ++i) {
        int t = threadIdx.x + 256 * i;
        int s_l = t & 63, oct = t >> 6;
        int m = mBase + s_l, bb = m >> 12, s = m & 4095;
        int cp = n0 + oct * 8;
        int hh = cp >> 5, dd0 = cp & 31;
        int bh = bb * Hn + hh;
        union { unsigned short us[8]; short8 s8; } pk;
#pragma unroll
        for (int e = 0; e < 8; ++e) pk.us[e] = f2bu(tl[oct * 8 + e][s_l]);
        if (proj == 0) {
          *(short8*)(qf + ((size_t)bh * Sn + s) * Dh + dd0) = pk.s8;
        } else {
          int fr = dd0 >> 4, ddl = (dd0 >> 3) & 1;
          size_t off = (size_t)bh * BHSZ +
                       (size_t)(((((s >> 5) * 2 + fr) * 64) + (s & 31) + 32 * ddl) * 8);
          *(short8*)(kswz + off) = pk.s8;
        }
      }
    } else {
#pragma unroll
      for (int i = 0; i < 2; ++i) {
        int t = threadIdx.x + 256 * i;
        int dd_l = t & 63, soct = t >> 6;
        int cp = n0 + dd_l;
        int hh = cp >> 5, dd = cp & 31;
        int m = mBase + soct * 8, bb = m >> 12, s = m & 4095;
        int bh = bb * Hn + hh;
        union { unsigned short us[8]; short8 s8; } pk;
#pragma unroll
        for (int e = 0; e < 8; ++e) pk.us[e] = f2bu(tl[dd_l][soct * 8 + e]);
        size_t off = (size_t)bh * BHSZ +
                     (size_t)(((((s >> 5) * 2 + ((s >> 4) & 1)) * 64) + dd + 32 * ((s >> 3) & 1)) * 8);
        *(short8*)(vswz + off) = pk.s8;
      }
    }
  }
}

// ---------------- flash attention: R15 proven body; epilogue writes of2 A-frag-major ----
// of2 layout (A-fragment-major over rows m = b*S+s, cols c):
//   off = ((m>>4)*8 + (c>>5))*512 + ((m&15) + 16*((c>>3)&3))*8 + (c&7)
// so k_oproj's A-load is base + frag*512 + lane*8 (coalesced).
__global__ __launch_bounds__(256, 4) void k_flash(
    const unsigned short* __restrict__ qf, const unsigned short* __restrict__ kswz,
    const unsigned short* __restrict__ vswz, unsigned short* __restrict__ of2) {
  int w = threadIdx.x >> 6, lane = threadIdx.x & 63;
  int l31 = lane & 31, hi = lane >> 5;
  int lin = blockIdx.x;                                // 0..1023
  int xcd = lin & 7, slot = lin >> 3;                  // 128 slots per XCD
  int bh = xcd + 8 * (slot >> 6);                      // 2 bh per XCD
  int q0 = (slot & 63) * 64;
  const unsigned short* Q = qf + (size_t)bh * Sn * Dh;

  short8 qa0 = *(const short8*)(Q + (size_t)(q0 + l31) * Dh + hi * 8);
  short8 qa1 = *(const short8*)(Q + (size_t)(q0 + l31) * Dh + 16 + hi * 8);
  short8 qc0 = *(const short8*)(Q + (size_t)(q0 + 32 + l31) * Dh + hi * 8);
  short8 qc1 = *(const short8*)(Q + (size_t)(q0 + 32 + l31) * Dh + 16 + hi * 8);

  floatx16 oaccA = {}, oaccB = {};  // O^T[d][q]: col q = l31, row d = (r&3)+8*(r>>2)+4*hi
  float lA = 0.f, lB = 0.f;
  const floatx16 zero16 = {};
  const unsigned short* Kc = kswz + (size_t)bh * BHSZ + (size_t)(w * 32) * 1024;
  const unsigned short* Vc = vswz + (size_t)bh * BHSZ + (size_t)(w * 32) * 1024;
  const int lofs = lane * 8;

  short8 kb0 = *(const short8*)(Kc + lofs);
  short8 kb1 = *(const short8*)(Kc + 512 + lofs);
  short8 vb0 = *(const short8*)(Vc + lofs);
  short8 vb1 = *(const short8*)(Vc + 512 + lofs);

  for (int it = 0; it < 32; ++it) {
    floatx16 sA = __builtin_amdgcn_mfma_f32_32x32x16_bf16(kb0, qa0, zero16, 0, 0, 0);
    sA = __builtin_amdgcn_mfma_f32_32x32x16_bf16(kb1, qa1, sA, 0, 0, 0);
    floatx16 sB = __builtin_amdgcn_mfma_f32_32x32x16_bf16(kb0, qc0, zero16, 0, 0, 0);
    sB = __builtin_amdgcn_mfma_f32_32x32x16_bf16(kb1, qc1, sB, 0, 0, 0);

    int nx = (it + 1) & 31;
    short8 nkb0 = *(const short8*)(Kc + nx * 1024 + lofs);
    short8 nkb1 = *(const short8*)(Kc + nx * 1024 + 512 + lofs);
    short8 nvb0 = *(const short8*)(Vc + nx * 1024 + lofs);
    short8 nvb1 = *(const short8*)(Vc + nx * 1024 + 512 + lofs);

#pragma unroll
    for (int i = 0; i < 16; ++i) sA[i] = __builtin_amdgcn_exp2f(sA[i]);
#pragma unroll
    for (int i = 0; i < 16; ++i) sB[i] = __builtin_amdgcn_exp2f(sB[i]);

    {
      float t0 = (sA[0] + sA[1]) + (sA[2] + sA[3]);
      float t1 = (sA[4] + sA[5]) + (sA[6] + sA[7]);
      float t2 = (sA[8] + sA[9]) + (sA[10] + sA[11]);
      float t3 = (sA[12] + sA[13]) + (sA[14] + sA[15]);
      lA += (t0 + t1) + (t2 + t3);
      float u0 = (sB[0] + sB[1]) + (sB[2] + sB[3]);
      float u1 = (sB[4] + sB[5]) + (sB[6] + sB[7]);
      float u2 = (sB[8] + sB[9]) + (sB[10] + sB[11]);
      float u3 = (sB[12] + sB[13]) + (sB[14] + sB[15]);
      lB += (u0 + u1) + (u2 + u3);
    }

    short8 fA0, fA1, fB0, fB1;
    pack_pt(sA, fA0, fA1);
    pack_pt(sB, fB0, fB1);

    oaccA = __builtin_amdgcn_mfma_f32_32x32x16_bf16(vb0, fA0, oaccA, 0, 0, 0);
    oaccA = __builtin_amdgcn_mfma_f32_32x32x16_bf16(vb1, fA1, oaccA, 0, 0, 0);
    oaccB = __builtin_amdgcn_mfma_f32_32x32x16_bf16(vb0, fB0, oaccB, 0, 0, 0);
    oaccB = __builtin_amdgcn_mfma_f32_32x32x16_bf16(vb1, fB1, oaccB, 0, 0, 0);

    kb0 = nkb0; kb1 = nkb1; vb0 = nvb0; vb1 = nvb1;
  }

  // cross-half l sums
  {
    float a = lA, b = lA;
    asm("v_permlane32_swap_b32 %0, %1" : "+v"(a), "+v"(b));
    lA = a + b;
    float c = lB, d = lB;
    asm("v_permlane32_swap_b32 %0, %1" : "+v"(c), "+v"(d));
    lB = c + d;
  }

  // ---- cross-wave combine via LDS (plain sums), then restage for frag-major write ----
  __shared__ float lsbuf[2 * NSPLIT * 16 * 64];   // 32KB, reused in two phases
  __shared__ float lm[2][NSPLIT][32];
#pragma unroll
  for (int r = 0; r < 16; ++r) {
    lsbuf[((0 * NSPLIT + w) * 16 + r) * 64 + lane] = oaccA[r];
    lsbuf[((1 * NSPLIT + w) * 16 + r) * 64 + lane] = oaccB[r];
  }
  if (!hi) { lm[0][w][l31] = lA; lm[1][w][l31] = lB; }
  __syncthreads();

  float LA = (lm[0][0][l31] + lm[0][1][l31]) + (lm[0][2][l31] + lm[0][3][l31]);
  float LB = (lm[1][0][l31] + lm[1][1][l31]) + (lm[1][2][l31] + lm[1][3][l31]);
  float invLA = 1.0f / LA, invLB = 1.0f / LB;
  float va4[4], vb4[4];
#pragma unroll
  for (int rr = 0; rr < 4; ++rr) {
    int r = w * 4 + rr;
    float va = 0.f, vb = 0.f;
#pragma unroll
    for (int i = 0; i < NSPLIT; ++i) {
      va += lsbuf[((0 * NSPLIT + i) * 16 + r) * 64 + lane];
      vb += lsbuf[((1 * NSPLIT + i) * 16 + r) * 64 + lane];
    }
    va4[rr] = va * invLA;
    vb4[rr] = vb * invLB;
  }
  __syncthreads();
#pragma unroll
  for (int rr = 0; rr < 4; ++rr) {
    int r = w * 4 + rr;
    int d = (r & 3) + 8 * (r >> 2) + 4 * hi;
    lsbuf[l31 * 33 + d]        = va4[rr];
    lsbuf[(32 + l31) * 33 + d] = vb4[rr];
  }
  __syncthreads();
  // write of2 A-fragment-major: thread t -> row qq = t>>2, col octet t&3 of head hh
  {
    int bb = bh >> 3, hh = bh & 7;
    int t = threadIdx.x;
    int qq = t >> 2, dg = (t & 3) * 8;
    union { unsigned short us[8]; short8 s8; } pk;
#pragma unroll
    for (int e = 0; e < 8; ++e) pk.us[e] = f2bu(lsbuf[qq * 33 + dg + e]);
    int m16 = ((bb * Sn + q0) >> 4) + (qq >> 4);
    size_t off = (size_t)(m16 * 8 + hh) * 512 + (size_t)(((qq & 15) + 16 * (t & 3)) * 8);
    *(short8*)(of2 + off) = pk.s8;
  }
}

// ---------------- output projection + residual: of2 A-frag-major, wswz B-frag-major ----
__global__ void k_oproj(const unsigned short* __restrict__ of2, const unsigned short* __restrict__ wo,
                        const float* __restrict__ bo, const float* __restrict__ x,
                        float* __restrict__ out) {
  int w = threadIdx.x >> 6, lane = threadIdx.x & 63;
  int lr = lane & 15, lg = lane >> 4;
  int m0 = blockIdx.x * 64 + w * 16;
  int n0 = blockIdx.y * 64;
  floatx4 acc[4] = {};
  for (int k0 = 0; k0 < 256; k0 += 32) {
    short8 a = *(const short8*)(of2 + (size_t)(((m0 >> 4) * 8 + (k0 >> 5)) * 512 + lane * 8));
#pragma unroll
    for (int nt = 0; nt < 4; ++nt) {
      short8 bfr = *(const short8*)(wo + (size_t)((((n0 >> 4) + nt) * 8 + (k0 >> 5)) * 512 + lane * 8));
      acc[nt] = __builtin_amdgcn_mfma_f32_16x16x32_bf16(a, bfr, acc[nt], 0, 0, 0);
    }
  }
  __shared__ float tl[64][65];
#pragma unroll
  for (int nt = 0; nt < 4; ++nt) {
    float bias = bo[n0 + nt * 16 + lr];
#pragma unroll
    for (int j = 0; j < 4; ++j)
      tl[w * 16 + lg * 4 + j][nt * 16 + lr] = acc[nt][j] + bias;
  }
  __syncthreads();
  int mBase = blockIdx.x * 64;
#pragma unroll
  for (int i = 0; i < 16; ++i) {
    int cl = i * 4 + (threadIdx.x >> 6);
    int ml = threadIdx.x & 63;
    int m = mBase + ml;
    int bb = m >> 12, s = m & 4095;
    size_t oi = ((size_t)(bb * Cdim + n0 + cl)) * Sn + s;
    out[oi] = tl[ml][cl] + x[oi];
  }
}

extern "C" void kernel_launch(void* const* d_in, const int* in_sizes, int n_in,
                              void* d_out, int out_size, void* d_ws, size_t ws_size,
                              hipStream_t stream) {
  const float* x  = (const float*)d_in[0];
  const float* gw = (const float*)d_in[1];
  const float* gb = (const float*)d_in[2];
  const float* Wq = (const float*)d_in[3];
  const float* bq = (const float*)d_in[4];
  const float* Wk = (const float*)d_in[5];
  const float* bk = (const float*)d_in[6];
  const float* Wv = (const float*)d_in[7];
  const float* bv = (const float*)d_in[8];
  const float* Wo = (const float*)d_in[9];
  const float* bo = (const float*)d_in[10];
  float* out = (float*)d_out;
  char* ws = (char*)d_ws;
  if (ws_size < 0x1482000) return;  // need ~20.5 MB scratch

  float* part  = (float*)(ws);              // 512*2 f32
  unsigned short* wall = (unsigned short*)(ws + 0x2000);    // 4 x 256x256 bf16 (B-frag-major)
  unsigned short* qf   = (unsigned short*)(ws + 0x482000);  // [B,H,S,32] bf16 (scaled, log2e folded)
  unsigned short* kswz = (unsigned short*)(ws + 0x882000);  // fragment-major K
  unsigned short* vswz = (unsigned short*)(ws + 0xC82000);  // fragment-major V^T
  unsigned short* of2  = (unsigned short*)(ws + 0x1082000); // [B*S, C] bf16 A-frag-major

  hipLaunchKernelGGL(k_pre, dim3(640), dim3(256), 0, stream, x, Wq, Wk, Wv, Wo, part, wall);
  hipLaunchKernelGGL(k_nqkv, dim3(128, 6), dim3(256), 0, stream, x, gw, gb, part, wall,
                     bq, bk, bv, qf, kswz, vswz);
  hipLaunchKernelGGL(k_flash, dim3(1024), dim3(256), 0, stream, qf, kswz, vswz, of2);
  hipLaunchKernelGGL(k_oproj, dim3(128, 4), dim3(256), 0, stream, of2, wall + 3 * 65536, bo, x, out);
}

// Round 17
// 79.294 us; speedup vs baseline: 1.7851x; 1.0241x over previous
//
#include <hip/hip_runtime.h>
#include <hip/hip_bf16.h>
#include <math.h>

#define Cdim 256
#define Hn 8
#define Bn 2
#define Sn 4096
#define Dh 32
#define GN_EPS 1e-5f
#define QK_SCALE 0.42044820762685725f   // 32^(-1/4), applied to BOTH q and k like the reference
#define LOG2E 1.4426950408889634f
#define NSPLIT 4
#define BHSZ (Sn * Dh)                  // elems per (b,h) in swizzled K/V
#define HLP 264                         // hl pitch in shorts (16B-aligned rows)

typedef __attribute__((ext_vector_type(8))) short short8;
typedef __attribute__((ext_vector_type(4))) float floatx4;
typedef __attribute__((ext_vector_type(16))) float floatx16;

__device__ __forceinline__ unsigned short f2bu(float x) {
  union { float f; unsigned u; } v; v.f = x;
  unsigned r = v.u + 0x7fffu + ((v.u >> 16) & 1u);  // RNE
  return (unsigned short)(r >> 16);
}

// pack 16 f32 probs -> two bf16x8 B-fragments via cvt_pk + permlane32_swap (T12)
__device__ __forceinline__ void pack_pt(const floatx16& p, short8& f0, short8& f1) {
  unsigned c0, c1, c2, c3, c4, c5, c6, c7;
  asm("v_cvt_pk_bf16_f32 %0, %1, %2" : "=v"(c0) : "v"(p[0]),  "v"(p[1]));
  asm("v_cvt_pk_bf16_f32 %0, %1, %2" : "=v"(c1) : "v"(p[2]),  "v"(p[3]));
  asm("v_cvt_pk_bf16_f32 %0, %1, %2" : "=v"(c2) : "v"(p[4]),  "v"(p[5]));
  asm("v_cvt_pk_bf16_f32 %0, %1, %2" : "=v"(c3) : "v"(p[6]),  "v"(p[7]));
  asm("v_cvt_pk_bf16_f32 %0, %1, %2" : "=v"(c4) : "v"(p[8]),  "v"(p[9]));
  asm("v_cvt_pk_bf16_f32 %0, %1, %2" : "=v"(c5) : "v"(p[10]), "v"(p[11]));
  asm("v_cvt_pk_bf16_f32 %0, %1, %2" : "=v"(c6) : "v"(p[12]), "v"(p[13]));
  asm("v_cvt_pk_bf16_f32 %0, %1, %2" : "=v"(c7) : "v"(p[14]), "v"(p[15]));
  asm("v_permlane32_swap_b32 %0, %1" : "+v"(c0), "+v"(c2));
  asm("v_permlane32_swap_b32 %0, %1" : "+v"(c1), "+v"(c3));
  asm("v_permlane32_swap_b32 %0, %1" : "+v"(c4), "+v"(c6));
  asm("v_permlane32_swap_b32 %0, %1" : "+v"(c5), "+v"(c7));
  union { unsigned u[4]; short8 s8; } a, b;
  a.u[0] = c0; a.u[1] = c1; a.u[2] = c2; a.u[3] = c3;
  b.u[0] = c4; b.u[1] = c5; b.u[2] = c6; b.u[3] = c7;
  f0 = a.s8; f1 = b.s8;
}

// ---------------- fused: GroupNorm partial stats (blocks 0-511) + weight cast+swizzle ----
// Weights written in B-FRAGMENT-MAJOR bf16: for W[n][k] (256x256),
//   off = ((n>>4)*8 + (k>>5))*512 + ((n&15) + 16*((k>>3)&3))*8 + (k&7)
__global__ void k_pre(const float* __restrict__ x,
                      const float* __restrict__ wq, const float* __restrict__ wk,
                      const float* __restrict__ wv, const float* __restrict__ wo,
                      float* __restrict__ part, unsigned short* __restrict__ wall) {
  if (blockIdx.x < 512) {
    int b = blockIdx.x >> 8;
    int base = (blockIdx.x & 255) * 4096 + b * (Cdim * Sn);
    float s = 0.f, ss = 0.f;
#pragma unroll
    for (int k = 0; k < 16; ++k) {
      float v = x[base + k * 256 + threadIdx.x];
      s += v; ss += v * v;
    }
    for (int off = 32; off; off >>= 1) { s += __shfl_down(s, off); ss += __shfl_down(ss, off); }
    __shared__ float as[4], bs[4];
    int w = threadIdx.x >> 6;
    if ((threadIdx.x & 63) == 0) { as[w] = s; bs[w] = ss; }
    __syncthreads();
    if (threadIdx.x == 0) {
      part[blockIdx.x * 2]     = as[0] + as[1] + as[2] + as[3];
      part[blockIdx.x * 2 + 1] = bs[0] + bs[1] + bs[2] + bs[3];
    }
  } else {
    int tid = (blockIdx.x - 512) * 256 + threadIdx.x;   // 0..32767
    int mat = tid >> 13;                                 // 0..3
    int idx = tid & 8191;                                // short8 id
    int n = idx >> 5, k8 = (idx & 31) * 8;
    const float* src = (mat == 0) ? wq : (mat == 1) ? wk : (mat == 2) ? wv : wo;
    union { unsigned short us[8]; short8 s8; } pk;
#pragma unroll
    for (int e = 0; e < 8; ++e) pk.us[e] = f2bu(src[n * 256 + k8 + e]);
    size_t off = (size_t)mat * 65536 +
                 (size_t)((((n >> 4) * 8 + (k8 >> 5)) * 512) + ((n & 15) + 16 * ((k8 >> 3) & 3)) * 8);
    *(short8*)(wall + off) = pk.s8;
  }
}

// ---------------- fused GroupNorm + QKV projection (frag-major W; XCD-grouped s-tiles) ----
// Block decode: xcd = lin&7, sb = xcd*16 + (rest&15), g = rest>>4 (proj*2+half).
// All 6 (proj,half) variants of an s-tile run on ONE XCD -> its 64KB x-tile is read from
// HBM once and L2-hit 5x (per-XCD working set 16 tiles = 1MB << 4MB L2).
__global__ void k_nqkv(const float* __restrict__ x, const float* __restrict__ gw,
                       const float* __restrict__ gb, const float* __restrict__ part,
                       const unsigned short* __restrict__ wall,
                       const float* __restrict__ bq, const float* __restrict__ bk,
                       const float* __restrict__ bv,
                       unsigned short* __restrict__ qf, unsigned short* __restrict__ kswz,
                       unsigned short* __restrict__ vswz) {
  int lin = blockIdx.x;                 // 0..767
  int xcd = lin & 7, rest = lin >> 3;   // rest 0..95
  int sb = xcd * 16 + (rest & 15);      // 0..127
  int g = rest >> 4;                    // 0..5
  int mBase = sb * 64;
  int b = sb >> 6;
  int proj = g >> 1, half = g & 1;
  int w = threadIdx.x >> 6, lane = threadIdx.x & 63;
  int lr = lane & 15, lg = lane >> 4;

  __shared__ float as[4], bs[4];
  {
    float s  = part[(b * 256 + threadIdx.x) * 2];
    float ss = part[(b * 256 + threadIdx.x) * 2 + 1];
    for (int off = 32; off; off >>= 1) { s += __shfl_down(s, off); ss += __shfl_down(ss, off); }
    if ((threadIdx.x & 63) == 0) { as[w] = s; bs[w] = ss; }
  }
  __syncthreads();
  const float invN = 1.f / (float)(Cdim * Sn);
  float mean = (as[0] + as[1] + as[2] + as[3]) * invN;
  float var  = (bs[0] + bs[1] + bs[2] + bs[3]) * invN - mean * mean;
  float rstd = rsqrtf(var + GN_EPS);

  __shared__ unsigned short hl[64][HLP];
  {
    int s0 = mBase & 4095;
    int rg = threadIdx.x >> 6;
#pragma unroll
    for (int i = 0; i < 32; ++i) {
      int cl = i * 8 + rg * 2;
      float v0 = x[((size_t)(b * Cdim + cl))     * Sn + s0 + lane];
      float v1 = x[((size_t)(b * Cdim + cl + 1)) * Sn + s0 + lane];
      float y0 = (v0 - mean) * rstd * gw[cl]     + gb[cl];
      float y1 = (v1 - mean) * rstd * gw[cl + 1] + gb[cl + 1];
      unsigned pkv = (unsigned)f2bu(y0) | ((unsigned)f2bu(y1) << 16);
      *(unsigned*)&hl[lane][cl] = pkv;
    }
  }
  __syncthreads();

  const unsigned short* W = wall + proj * 65536;
  __shared__ float tl[64][65];
  for (int sub = 0; sub < 2; ++sub) {
    int n0 = half * 128 + sub * 64;
    floatx4 acc[4] = {};
    for (int k0 = 0; k0 < 256; k0 += 32) {
      short8 a = *(const short8*)&hl[w * 16 + lr][k0 + lg * 8];
#pragma unroll
      for (int nt = 0; nt < 4; ++nt) {
        short8 bfr = *(const short8*)(W + (size_t)((((n0 >> 4) + nt) * 8 + (k0 >> 5)) * 512 + lane * 8));
        acc[nt] = __builtin_amdgcn_mfma_f32_16x16x32_bf16(a, bfr, acc[nt], 0, 0, 0);
      }
    }
    if (sub) __syncthreads();
    {
      const float* bias = (proj == 0) ? bq : (proj == 1 ? bk : bv);
      float scale = (proj == 0) ? (QK_SCALE * LOG2E) : (proj == 1 ? QK_SCALE : 1.f);
#pragma unroll
      for (int nt = 0; nt < 4; ++nt) {
        int nl = nt * 16 + lr;
        float bias_n = bias[n0 + nl];
#pragma unroll
        for (int j = 0; j < 4; ++j)
          tl[nl][w * 16 + lg * 4 + j] = (acc[nt][j] + bias_n) * scale;
      }
    }
    __syncthreads();
    if (proj < 2) {
#pragma unroll
      for (int i = 0; i < 2; ++i) {
        int t = threadIdx.x + 256 * i;
        int s_l = t & 63, oct = t >> 6;
        int m = mBase + s_l, bb = m >> 12, s = m & 4095;
        int cp = n0 + oct * 8;
        int hh = cp >> 5, dd0 = cp & 31;
        int bh = bb * Hn + hh;
        union { unsigned short us[8]; short8 s8; } pk;
#pragma unroll
        for (int e = 0; e < 8; ++e) pk.us[e] = f2bu(tl[oct * 8 + e][s_l]);
        if (proj == 0) {
          *(short8*)(qf + ((size_t)bh * Sn + s) * Dh + dd0) = pk.s8;
        } else {
          int fr = dd0 >> 4, ddl = (dd0 >> 3) & 1;
          size_t off = (size_t)bh * BHSZ +
                       (size_t)(((((s >> 5) * 2 + fr) * 64) + (s & 31) + 32 * ddl) * 8);
          *(short8*)(kswz + off) = pk.s8;
        }
      }
    } else {
#pragma unroll
      for (int i = 0; i < 2; ++i) {
        int t = threadIdx.x + 256 * i;
        int dd_l = t & 63, soct = t >> 6;
        int cp = n0 + dd_l;
        int hh = cp >> 5, dd = cp & 31;
        int m = mBase + soct * 8, bb = m >> 12, s = m & 4095;
        int bh = bb * Hn + hh;
        union { unsigned short us[8]; short8 s8; } pk;
#pragma unroll
        for (int e = 0; e < 8; ++e) pk.us[e] = f2bu(tl[dd_l][soct * 8 + e]);
        size_t off = (size_t)bh * BHSZ +
                     (size_t)(((((s >> 5) * 2 + ((s >> 4) & 1)) * 64) + dd + 32 * ((s >> 3) & 1)) * 8);
        *(short8*)(vswz + off) = pk.s8;
      }
    }
  }
}

// ---------------- flash attention: R15 proven body; epilogue writes of2 A-frag-major ----
__global__ __launch_bounds__(256, 4) void k_flash(
    const unsigned short* __restrict__ qf, const unsigned short* __restrict__ kswz,
    const unsigned short* __restrict__ vswz, unsigned short* __restrict__ of2) {
  int w = threadIdx.x >> 6, lane = threadIdx.x & 63;
  int l31 = lane & 31, hi = lane >> 5;
  int lin = blockIdx.x;                                // 0..1023
  int xcd = lin & 7, slot = lin >> 3;                  // 128 slots per XCD
  int bh = xcd + 8 * (slot >> 6);                      // 2 bh per XCD
  int q0 = (slot & 63) * 64;
  const unsigned short* Q = qf + (size_t)bh * Sn * Dh;

  short8 qa0 = *(const short8*)(Q + (size_t)(q0 + l31) * Dh + hi * 8);
  short8 qa1 = *(const short8*)(Q + (size_t)(q0 + l31) * Dh + 16 + hi * 8);
  short8 qc0 = *(const short8*)(Q + (size_t)(q0 + 32 + l31) * Dh + hi * 8);
  short8 qc1 = *(const short8*)(Q + (size_t)(q0 + 32 + l31) * Dh + 16 + hi * 8);

  floatx16 oaccA = {}, oaccB = {};  // O^T[d][q]: col q = l31, row d = (r&3)+8*(r>>2)+4*hi
  float lA = 0.f, lB = 0.f;
  const floatx16 zero16 = {};
  const unsigned short* Kc = kswz + (size_t)bh * BHSZ + (size_t)(w * 32) * 1024;
  const unsigned short* Vc = vswz + (size_t)bh * BHSZ + (size_t)(w * 32) * 1024;
  const int lofs = lane * 8;

  short8 kb0 = *(const short8*)(Kc + lofs);
  short8 kb1 = *(const short8*)(Kc + 512 + lofs);
  short8 vb0 = *(const short8*)(Vc + lofs);
  short8 vb1 = *(const short8*)(Vc + 512 + lofs);

  for (int it = 0; it < 32; ++it) {
    floatx16 sA = __builtin_amdgcn_mfma_f32_32x32x16_bf16(kb0, qa0, zero16, 0, 0, 0);
    sA = __builtin_amdgcn_mfma_f32_32x32x16_bf16(kb1, qa1, sA, 0, 0, 0);
    floatx16 sB = __builtin_amdgcn_mfma_f32_32x32x16_bf16(kb0, qc0, zero16, 0, 0, 0);
    sB = __builtin_amdgcn_mfma_f32_32x32x16_bf16(kb1, qc1, sB, 0, 0, 0);

    int nx = (it + 1) & 31;
    short8 nkb0 = *(const short8*)(Kc + nx * 1024 + lofs);
    short8 nkb1 = *(const short8*)(Kc + nx * 1024 + 512 + lofs);
    short8 nvb0 = *(const short8*)(Vc + nx * 1024 + lofs);
    short8 nvb1 = *(const short8*)(Vc + nx * 1024 + 512 + lofs);

#pragma unroll
    for (int i = 0; i < 16; ++i) sA[i] = __builtin_amdgcn_exp2f(sA[i]);
#pragma unroll
    for (int i = 0; i < 16; ++i) sB[i] = __builtin_amdgcn_exp2f(sB[i]);

    {
      float t0 = (sA[0] + sA[1]) + (sA[2] + sA[3]);
      float t1 = (sA[4] + sA[5]) + (sA[6] + sA[7]);
      float t2 = (sA[8] + sA[9]) + (sA[10] + sA[11]);
      float t3 = (sA[12] + sA[13]) + (sA[14] + sA[15]);
      lA += (t0 + t1) + (t2 + t3);
      float u0 = (sB[0] + sB[1]) + (sB[2] + sB[3]);
      float u1 = (sB[4] + sB[5]) + (sB[6] + sB[7]);
      float u2 = (sB[8] + sB[9]) + (sB[10] + sB[11]);
      float u3 = (sB[12] + sB[13]) + (sB[14] + sB[15]);
      lB += (u0 + u1) + (u2 + u3);
    }

    short8 fA0, fA1, fB0, fB1;
    pack_pt(sA, fA0, fA1);
    pack_pt(sB, fB0, fB1);

    oaccA = __builtin_amdgcn_mfma_f32_32x32x16_bf16(vb0, fA0, oaccA, 0, 0, 0);
    oaccA = __builtin_amdgcn_mfma_f32_32x32x16_bf16(vb1, fA1, oaccA, 0, 0, 0);
    oaccB = __builtin_amdgcn_mfma_f32_32x32x16_bf16(vb0, fB0, oaccB, 0, 0, 0);
    oaccB = __builtin_amdgcn_mfma_f32_32x32x16_bf16(vb1, fB1, oaccB, 0, 0, 0);

    kb0 = nkb0; kb1 = nkb1; vb0 = nvb0; vb1 = nvb1;
  }

  // cross-half l sums
  {
    float a = lA, b = lA;
    asm("v_permlane32_swap_b32 %0, %1" : "+v"(a), "+v"(b));
    lA = a + b;
    float c = lB, d = lB;
    asm("v_permlane32_swap_b32 %0, %1" : "+v"(c), "+v"(d));
    lB = c + d;
  }

  // ---- cross-wave combine via LDS (plain sums), then restage for frag-major write ----
  __shared__ float lsbuf[2 * NSPLIT * 16 * 64];   // 32KB, reused in two phases
  __shared__ float lm[2][NSPLIT][32];
#pragma unroll
  for (int r = 0; r < 16; ++r) {
    lsbuf[((0 * NSPLIT + w) * 16 + r) * 64 + lane] = oaccA[r];
    lsbuf[((1 * NSPLIT + w) * 16 + r) * 64 + lane] = oaccB[r];
  }
  if (!hi) { lm[0][w][l31] = lA; lm[1][w][l31] = lB; }
  __syncthreads();

  float LA = (lm[0][0][l31] + lm[0][1][l31]) + (lm[0][2][l31] + lm[0][3][l31]);
  float LB = (lm[1][0][l31] + lm[1][1][l31]) + (lm[1][2][l31] + lm[1][3][l31]);
  float invLA = 1.0f / LA, invLB = 1.0f / LB;
  float va4[4], vb4[4];
#pragma unroll
  for (int rr = 0; rr < 4; ++rr) {
    int r = w * 4 + rr;
    float va = 0.f, vb = 0.f;
#pragma unroll
    for (int i = 0; i < NSPLIT; ++i) {
      va += lsbuf[((0 * NSPLIT + i) * 16 + r) * 64 + lane];
      vb += lsbuf[((1 * NSPLIT + i) * 16 + r) * 64 + lane];
    }
    va4[rr] = va * invLA;
    vb4[rr] = vb * invLB;
  }
  __syncthreads();
#pragma unroll
  for (int rr = 0; rr < 4; ++rr) {
    int r = w * 4 + rr;
    int d = (r & 3) + 8 * (r >> 2) + 4 * hi;
    lsbuf[l31 * 33 + d]        = va4[rr];
    lsbuf[(32 + l31) * 33 + d] = vb4[rr];
  }
  __syncthreads();
  {
    int bb = bh >> 3, hh = bh & 7;
    int t = threadIdx.x;
    int qq = t >> 2, dg = (t & 3) * 8;
    union { unsigned short us[8]; short8 s8; } pk;
#pragma unroll
    for (int e = 0; e < 8; ++e) pk.us[e] = f2bu(lsbuf[qq * 33 + dg + e]);
    int m16 = ((bb * Sn + q0) >> 4) + (qq >> 4);
    size_t off = (size_t)(m16 * 8 + hh) * 512 + (size_t)(((qq & 15) + 16 * (t & 3)) * 8);
    *(short8*)(of2 + off) = pk.s8;
  }
}

// ---------------- output projection + residual: of2 A-frag-major, wall B-frag-major ----
__global__ void k_oproj(const unsigned short* __restrict__ of2, const unsigned short* __restrict__ wo,
                        const float* __restrict__ bo, const float* __restrict__ x,
                        float* __restrict__ out) {
  int w = threadIdx.x >> 6, lane = threadIdx.x & 63;
  int lr = lane & 15, lg = lane >> 4;
  int m0 = blockIdx.x * 64 + w * 16;
  int n0 = blockIdx.y * 64;
  floatx4 acc[4] = {};
  for (int k0 = 0; k0 < 256; k0 += 32) {
    short8 a = *(const short8*)(of2 + (size_t)(((m0 >> 4) * 8 + (k0 >> 5)) * 512 + lane * 8));
#pragma unroll
    for (int nt = 0; nt < 4; ++nt) {
      short8 bfr = *(const short8*)(wo + (size_t)((((n0 >> 4) + nt) * 8 + (k0 >> 5)) * 512 + lane * 8));
      acc[nt] = __builtin_amdgcn_mfma_f32_16x16x32_bf16(a, bfr, acc[nt], 0, 0, 0);
    }
  }
  __shared__ float tl[64][65];
#pragma unroll
  for (int nt = 0; nt < 4; ++nt) {
    float bias = bo[n0 + nt * 16 + lr];
#pragma unroll
    for (int j = 0; j < 4; ++j)
      tl[w * 16 + lg * 4 + j][nt * 16 + lr] = acc[nt][j] + bias;
  }
  __syncthreads();
  int mBase = blockIdx.x * 64;
#pragma unroll
  for (int i = 0; i < 16; ++i) {
    int cl = i * 4 + (threadIdx.x >> 6);
    int ml = threadIdx.x & 63;
    int m = mBase + ml;
    int bb = m >> 12, s = m & 4095;
    size_t oi = ((size_t)(bb * Cdim + n0 + cl)) * Sn + s;
    out[oi] = tl[ml][cl] + x[oi];
  }
}

extern "C" void kernel_launch(void* const* d_in, const int* in_sizes, int n_in,
                              void* d_out, int out_size, void* d_ws, size_t ws_size,
                              hipStream_t stream) {
  const float* x  = (const float*)d_in[0];
  const float* gw = (const float*)d_in[1];
  const float* gb = (const float*)d_in[2];
  const float* Wq = (const float*)d_in[3];
  const float* bq = (const float*)d_in[4];
  const float* Wk = (const float*)d_in[5];
  const float* bk = (const float*)d_in[6];
  const float* Wv = (const float*)d_in[7];
  const float* bv = (const float*)d_in[8];
  const float* Wo = (const float*)d_in[9];
  const float* bo = (const float*)d_in[10];
  float* out = (float*)d_out;
  char* ws = (char*)d_ws;
  if (ws_size < 0x1482000) return;  // need ~20.5 MB scratch

  float* part  = (float*)(ws);              // 512*2 f32
  unsigned short* wall = (unsigned short*)(ws + 0x2000);    // 4 x 256x256 bf16 (B-frag-major)
  unsigned short* qf   = (unsigned short*)(ws + 0x482000);  // [B,H,S,32] bf16 (scaled, log2e folded)
  unsigned short* kswz = (unsigned short*)(ws + 0x882000);  // fragment-major K
  unsigned short* vswz = (unsigned short*)(ws + 0xC82000);  // fragment-major V^T
  unsigned short* of2  = (unsigned short*)(ws + 0x1082000); // [B*S, C] bf16 A-frag-major

  hipLaunchKernelGGL(k_pre, dim3(640), dim3(256), 0, stream, x, Wq, Wk, Wv, Wo, part, wall);
  hipLaunchKernelGGL(k_nqkv, dim3(768), dim3(256), 0, stream, x, gw, gb, part, wall,
                     bq, bk, bv, qf, kswz, vswz);
  hipLaunchKernelGGL(k_flash, dim3(1024), dim3(256), 0, stream, qf, kswz, vswz, of2);
  hipLaunchKernelGGL(k_oproj, dim3(128, 4), dim3(256), 0, stream, of2, wall + 3 * 65536, bo, x, out);
}